// Round 6
// baseline (68.151 us; speedup 1.0000x reference)
//
#include <hip/hip_runtime.h>

#define CD_B 4
#define CD_N 4096
#define CD_M 4096
#define TILE 256

// Fills both min arrays (contiguous, 32768 uints) with +inf bits via uint4
// stores, and zeroes the output scalar for cd_reduce's atomicAdd.
__global__ __launch_bounds__(256) void cd_init(uint4* __restrict__ mins,
                                               float* __restrict__ out) {
    if (blockIdx.x == 0 && threadIdx.x == 0) out[0] = 0.f;
    const unsigned int inf = 0x7F800000u;
    mins[blockIdx.x * 256 + threadIdx.x] = make_uint4(inf, inf, inf, inf);
}

// Grid: 4 batches x 16 recon-tiles x 16 gt-tiles = 1024 blocks, 256 threads.
// Tile 256x256. LDS tiles hold (x,y,z,|.|^2); distance via
//   |p-g|^2 = |p|^2 + (|g|^2 - 2 p.g)
// so the inner pair costs 3 FMA + amortized min3 (3.5 VALU ops/pair).
// Each lane owns 4 points (independent min chains -> ILP); the 4 waves split
// the streamed dimension 64 each. Partial mins combine via LDS, then one
// atomicMin (uint bits, values >= 0 so uint order == float order) per point
// per phase.
__global__ __launch_bounds__(256, 4) void cd_main(const float* __restrict__ recon,
                                                  const float* __restrict__ gt,
                                                  unsigned int* __restrict__ rmin,
                                                  unsigned int* __restrict__ cmin) {
    const int bid = blockIdx.x;
    const int b   = bid >> 8;
    const int ti  = (bid >> 4) & 15;
    const int tj  = bid & 15;
    const int t   = threadIdx.x;
    const int w   = t >> 6;   // wave 0..3
    const int l   = t & 63;   // lane

    __shared__ float4 rs[TILE];        // (x, y, z, |p|^2)
    __shared__ float4 gs[TILE];
    __shared__ float  part[4][TILE];

    {   // Stage: thread t loads point t of each tile, computes its norm.
        const float* rp = recon + ((size_t)(b * CD_N + ti * TILE) + t) * 3;
        const float* gp = gt    + ((size_t)(b * CD_M + tj * TILE) + t) * 3;
        const float rx = rp[0], ry = rp[1], rz = rp[2];
        const float gx = gp[0], gy = gp[1], gz = gp[2];
        rs[t] = make_float4(rx, ry, rz, fmaf(rz, rz, fmaf(ry, ry, rx * rx)));
        gs[t] = make_float4(gx, gy, gz, fmaf(gz, gz, fmaf(gy, gy, gx * gx)));
    }
    __syncthreads();

    const float INF = __builtin_inff();

    // ---- Phase 1: rowmin. Lane l owns recon rows {l,64+l,128+l,192+l};
    //      wave w streams gt cols [64w, 64w+64).
    {
        const float4 p0 = rs[l], p1 = rs[64 + l], p2 = rs[128 + l], p3 = rs[192 + l];
        const float a0x = -2.f * p0.x, a0y = -2.f * p0.y, a0z = -2.f * p0.z;
        const float a1x = -2.f * p1.x, a1y = -2.f * p1.y, a1z = -2.f * p1.z;
        const float a2x = -2.f * p2.x, a2y = -2.f * p2.y, a2z = -2.f * p2.z;
        const float a3x = -2.f * p3.x, a3y = -2.f * p3.y, a3z = -2.f * p3.z;
        float m0 = INF, m1 = INF, m2 = INF, m3 = INF;
        const int jbase = w << 6;
        #pragma unroll 8
        for (int jj = 0; jj < 64; jj += 2) {
            const float4 g0 = gs[jbase + jj];       // broadcast ds_read_b128
            const float4 g1 = gs[jbase + jj + 1];
            float d0, d1;
            d0 = fmaf(a0x, g0.x, fmaf(a0y, g0.y, fmaf(a0z, g0.z, g0.w)));
            d1 = fmaf(a0x, g1.x, fmaf(a0y, g1.y, fmaf(a0z, g1.z, g1.w)));
            m0 = fminf(fminf(d0, d1), m0);          // fuses to v_min3_f32
            d0 = fmaf(a1x, g0.x, fmaf(a1y, g0.y, fmaf(a1z, g0.z, g0.w)));
            d1 = fmaf(a1x, g1.x, fmaf(a1y, g1.y, fmaf(a1z, g1.z, g1.w)));
            m1 = fminf(fminf(d0, d1), m1);
            d0 = fmaf(a2x, g0.x, fmaf(a2y, g0.y, fmaf(a2z, g0.z, g0.w)));
            d1 = fmaf(a2x, g1.x, fmaf(a2y, g1.y, fmaf(a2z, g1.z, g1.w)));
            m2 = fminf(fminf(d0, d1), m2);
            d0 = fmaf(a3x, g0.x, fmaf(a3y, g0.y, fmaf(a3z, g0.z, g0.w)));
            d1 = fmaf(a3x, g1.x, fmaf(a3y, g1.y, fmaf(a3z, g1.z, g1.w)));
            m3 = fminf(fminf(d0, d1), m3);
        }
        part[w][l]       = m0;
        part[w][64 + l]  = m1;
        part[w][128 + l] = m2;
        part[w][192 + l] = m3;
    }
    __syncthreads();
    {   // combine wave partials for row t, add |p|^2, clamp >= 0, one atomic
        const float v = fminf(fminf(part[0][t], part[1][t]),
                              fminf(part[2][t], part[3][t]));
        const float dist = fmaxf(v + rs[t].w, 0.f);
        atomicMin(&rmin[b * CD_N + ti * TILE + t], __float_as_uint(dist));
    }
    __syncthreads();  // part[] reused below

    // ---- Phase 2: colmin. Lane l owns gt cols; wave w streams recon rows.
    {
        const float4 q0 = gs[l], q1 = gs[64 + l], q2 = gs[128 + l], q3 = gs[192 + l];
        const float a0x = -2.f * q0.x, a0y = -2.f * q0.y, a0z = -2.f * q0.z;
        const float a1x = -2.f * q1.x, a1y = -2.f * q1.y, a1z = -2.f * q1.z;
        const float a2x = -2.f * q2.x, a2y = -2.f * q2.y, a2z = -2.f * q2.z;
        const float a3x = -2.f * q3.x, a3y = -2.f * q3.y, a3z = -2.f * q3.z;
        float m0 = INF, m1 = INF, m2 = INF, m3 = INF;
        const int ibase = w << 6;
        #pragma unroll 8
        for (int ii = 0; ii < 64; ii += 2) {
            const float4 r0 = rs[ibase + ii];
            const float4 r1 = rs[ibase + ii + 1];
            float d0, d1;
            d0 = fmaf(a0x, r0.x, fmaf(a0y, r0.y, fmaf(a0z, r0.z, r0.w)));
            d1 = fmaf(a0x, r1.x, fmaf(a0y, r1.y, fmaf(a0z, r1.z, r1.w)));
            m0 = fminf(fminf(d0, d1), m0);
            d0 = fmaf(a1x, r0.x, fmaf(a1y, r0.y, fmaf(a1z, r0.z, r0.w)));
            d1 = fmaf(a1x, r1.x, fmaf(a1y, r1.y, fmaf(a1z, r1.z, r1.w)));
            m1 = fminf(fminf(d0, d1), m1);
            d0 = fmaf(a2x, r0.x, fmaf(a2y, r0.y, fmaf(a2z, r0.z, r0.w)));
            d1 = fmaf(a2x, r1.x, fmaf(a2y, r1.y, fmaf(a2z, r1.z, r1.w)));
            m2 = fminf(fminf(d0, d1), m2);
            d0 = fmaf(a3x, r0.x, fmaf(a3y, r0.y, fmaf(a3z, r0.z, r0.w)));
            d1 = fmaf(a3x, r1.x, fmaf(a3y, r1.y, fmaf(a3z, r1.z, r1.w)));
            m3 = fminf(fminf(d0, d1), m3);
        }
        part[w][l]       = m0;
        part[w][64 + l]  = m1;
        part[w][128 + l] = m2;
        part[w][192 + l] = m3;
    }
    __syncthreads();
    {
        const float v = fminf(fminf(part[0][t], part[1][t]),
                              fminf(part[2][t], part[3][t]));
        const float dist = fmaxf(v + gs[t].w, 0.f);
        atomicMin(&cmin[b * CD_M + tj * TILE + t], __float_as_uint(dist));
    }
}

// 64 blocks, grid-stride over both min arrays (contiguous), atomicAdd the
// pre-scaled partial into out[0] (zeroed by cd_init).
__global__ __launch_bounds__(256) void cd_reduce(const unsigned int* __restrict__ mins,
                                                 float* __restrict__ out) {
    const int total = CD_B * (CD_N + CD_M);
    float s = 0.f;
    for (int i = blockIdx.x * 256 + threadIdx.x; i < total; i += 64 * 256)
        s += __uint_as_float(mins[i]);
    for (int off = 32; off; off >>= 1) s += __shfl_down(s, off);
    __shared__ float ws[4];
    const int t = threadIdx.x;
    if ((t & 63) == 0) ws[t >> 6] = s;
    __syncthreads();
    if (t == 0) {
        const float tot = ws[0] + ws[1] + ws[2] + ws[3];
        atomicAdd(out, tot * (0.5f / (float)(CD_B * CD_N)));  // N == M
    }
}

extern "C" void kernel_launch(void* const* d_in, const int* in_sizes, int n_in,
                              void* d_out, int out_size, void* d_ws, size_t ws_size,
                              hipStream_t stream) {
    const float* recon = (const float*)d_in[0];
    const float* gt    = (const float*)d_in[1];
    unsigned int* rmin = (unsigned int*)d_ws;        // B*N entries
    unsigned int* cmin = rmin + CD_B * CD_N;         // B*M entries (contiguous)
    float* out = (float*)d_out;

    // 32768 uints = 8192 uint4 -> 32 blocks of 256 threads
    cd_init<<<32, 256, 0, stream>>>((uint4*)rmin, out);
    cd_main<<<CD_B * 16 * 16, 256, 0, stream>>>(recon, gt, rmin, cmin);
    cd_reduce<<<64, 256, 0, stream>>>(rmin, out);
}